// Round 9
// baseline (217.562 us; speedup 1.0000x reference)
//
#include <hip/hip_runtime.h>
#include <math.h>

// Problem constants (fixed by reference setup_inputs)
#define T_TOK 16384
#define DDIM  2048
#define NE    64
#define NPLANE (NE * DDIM)      // 131072 elements per W split plane
#define NBLK  512               // main-kernel grid (32 tokens each)

typedef __attribute__((ext_vector_type(8))) short short8;   // 8 bf16 MFMA frag
typedef __attribute__((ext_vector_type(4))) float floatx4;  // MFMA C/D

union Frag8 { unsigned short u[8]; short8 v; };

__device__ __forceinline__ unsigned int bf16_rne_bits(float x) {
    unsigned int u = __builtin_bit_cast(unsigned int, x);
    return (u + 0x7fffu + ((u >> 16) & 1u)) & 0xffff0000u;
}

// ---- pre-kernel: exact 3-way bf16 split of W, PACKED in MFMA-frag order ----
// packed idx = ((kc*4 + et)*4 + q)*128 + cl*8 + j
//   expert e = et*16 + cl,  k = kc*32 + q*8 + j
// => a wave's B-frag load (fixed p, kc, et; lanes (q,cl)) is 1 KB contiguous.
__global__ void wsplit_kernel(const float* __restrict__ W,
                              unsigned short* __restrict__ wh,
                              unsigned short* __restrict__ wm,
                              unsigned short* __restrict__ wl) {
    int i  = blockIdx.x * 256 + threadIdx.x;   // grid covers exactly NPLANE
    int j  = i & 7;
    int cl = (i >> 3) & 15;
    int q  = (i >> 7) & 3;
    int et = (i >> 9) & 3;
    int kc = i >> 11;                          // 0..63
    int e  = et * 16 + cl;
    int k  = kc * 32 + q * 8 + j;
    float w = W[e * DDIM + k];
    unsigned int hb = bf16_rne_bits(w);
    float r  = w - __builtin_bit_cast(float, hb);   // exact
    unsigned int mb = bf16_rne_bits(r);
    float r2 = r - __builtin_bit_cast(float, mb);   // exact
    unsigned int lb = bf16_rne_bits(r2);            // |err| <= 2^-24 |w|
    wh[i] = (unsigned short)(hb >> 16);
    wm[i] = (unsigned short)(mb >> 16);
    wl[i] = (unsigned short)(lb >> 16);
}

// ---- main: R8 arithmetic, REG-STAGED 3-slot ring with 2-window lookahead.
// Window w (256 k) lives in ring slot w%3. Phase c: [barrier from prev] ->
// B loads (6, FIFO-first: retire at vmcnt(2)) -> x loads for window c+2
// (2 x global_load_dwordx4, linear source; stay in flight across the whole
// phase) -> ds_reads+split+MFMA on slot c%3 -> ds_write window c+2 into slot
// (c+2)%3 (XOR swizzle on the write address => LDS image bit-identical to
// R8's pre-swizzled-source DMA) -> barrier. The barrier's vmcnt(0) is a
// no-op (all VMEM already retired), and the x-loads get a full phase of
// latency cover via plain vector loads (the 6.3 TB/s-proven request type)
// instead of the 16B-granule global_load_lds path.
// Slot safety: writes target (c+2)%3, reads target c%3; distinct mod 3, and
// slot c%3 is only rewritten (as window c+3) during phase c+1, after the
// end-of-phase-c barrier has ordered all phase-c reads before it.
// LDS: As[3][8192] f32 = 96 KB (lg[8][32][64] overlays slot 0 after the
// loop) + ured 4 KB -> 1 block/CU.
__global__ __launch_bounds__(1024, 4)
void router_main(const float* __restrict__ x,
                 const unsigned short* __restrict__ wh,
                 const unsigned short* __restrict__ wm,
                 const unsigned short* __restrict__ wl,
                 float* __restrict__ out, float* __restrict__ usage_part) {
    __shared__ float As[3 * 8192];     // 96 KB ring; lg overlays after loop
    __shared__ float ured[16][NE];     // 4 KB
    float* lg = As;                    // [8][32][64] overlay (written post-loop)

    const int tid  = threadIdx.x;
    const int lane = tid & 63;
    const int wv   = __builtin_amdgcn_readfirstlane(tid >> 6);  // 0..15
    const int nh   = wv & 1;     // expert half (32 experts)
    const int kq   = wv >> 1;    // k sub-slice within each 256-k window
    const int cl   = lane & 15;  // frag row index (token / expert)
    const int q    = lane >> 4;  // frag k-quad
    const int t0   = blockIdx.x * 32;

    // A staging role: wave stages local tokens 2wv, 2wv+1.
    // Linear global source (lane l -> 16-B chunk l of the 1 KB window);
    // XOR swizzle (chunk ^ (tl&7)) applied on the ds_write address =>
    // LDS[tl][c'] = x[tl][c'^s], identical image to R4/R7/R8.
    const int tlA0 = 2 * wv, tlA1 = 2 * wv + 1;
    const float* ax0 = x + (size_t)(t0 + tlA0) * DDIM + (lane << 2);
    const float* ax1 = x + (size_t)(t0 + tlA1) * DDIM + (lane << 2);
    const int wofs0 = tlA0 * 256 + ((lane ^ (tlA0 & 7)) << 2);
    const int wofs1 = tlA1 * 256 + ((lane ^ (tlA1 & 7)) << 2);

    floatx4 acc[2][2];
#pragma unroll
    for (int mt = 0; mt < 2; ++mt)
#pragma unroll
        for (int nt = 0; nt < 2; ++nt)
            acc[mt][nt] = (floatx4){0.f, 0.f, 0.f, 0.f};

    // B frag element offsets (phase c adds c*16384):
    //   ((c*8 + kq)*4 + (nh*2+nt))*512 + (q*16+cl)*8
    const unsigned lofs   = (unsigned)((q * 16 + cl) << 3);
    const unsigned bfrag0 = ((unsigned)(kq * 4 + nh * 2 + 0) << 9) + lofs;
    const unsigned bfrag1 = ((unsigned)(kq * 4 + nh * 2 + 1) << 9) + lofs;

    // prologue: stage windows 0,1 -> slots 0,1 (reg-staged, serial)
    {
        float4 p0 = *(const float4*)(ax0);
        float4 p1 = *(const float4*)(ax1);
        float4 p2 = *(const float4*)(ax0 + 256);
        float4 p3 = *(const float4*)(ax1 + 256);
        *(float4*)(As + wofs0) = p0;
        *(float4*)(As + wofs1) = p1;
        *(float4*)(As + 8192 + wofs0) = p2;
        *(float4*)(As + 8192 + wofs1) = p3;
    }
    __syncthreads();   // slots 0,1 published

    int rs = 0;        // read slot: window c   -> slot c%3
    int ws2 = 2;       // write slot: window c+2 -> slot (c+2)%3
#pragma unroll 1
    for (int c = 0; c < 8; ++c) {
        // B frags FIRST: two 1-KB contiguous loads x 3 planes.
        // FIFO: [B x6][x x2] -> the wait before B use is vmcnt(2), leaving
        // the x loads in flight for the rest of the phase.
        const unsigned bo = (unsigned)c * 16384u;
        uint4 cb[2][3];
        {
            const unsigned o0 = bo + bfrag0, o1 = bo + bfrag1;
            cb[0][0] = *(const uint4*)(wh + o0);
            cb[0][1] = *(const uint4*)(wm + o0);
            cb[0][2] = *(const uint4*)(wl + o0);
            cb[1][0] = *(const uint4*)(wh + o1);
            cb[1][1] = *(const uint4*)(wm + o1);
            cb[1][2] = *(const uint4*)(wl + o1);
        }
        __builtin_amdgcn_sched_barrier(0);   // pin: B issued first

        // x loads for window c+2 (uniform branch; no divergence)
        float4 n0, n1;
        if (c + 2 < 8) {
            n0 = *(const float4*)(ax0 + (c + 2) * 256);
            n1 = *(const float4*)(ax1 + (c + 2) * 256);
        }
        __builtin_amdgcn_sched_barrier(0);   // pin: x issued early

        // A frags from LDS slot c%3 (chunk-XOR by cl&7) + 3-way split
        const float* buf = As + rs * 8192;
        const int h0 = (kq * 8 + q * 2) ^ (cl & 7);   // swizzled 16-B chunk idx
        short8 Ah[2], Am[2], Al[2];
#pragma unroll
        for (int mt = 0; mt < 2; ++mt) {
            const float* ap = buf + (mt * 16 + cl) * 256;
            float4 a0 = *(const float4*)(ap + h0 * 4);         // k j=0..3
            float4 a1 = *(const float4*)(ap + (h0 ^ 1) * 4);   // k j=4..7
            float f[8] = {a0.x, a0.y, a0.z, a0.w, a1.x, a1.y, a1.z, a1.w};
            Frag8 fh, fm, fl;
#pragma unroll
            for (int j = 0; j < 8; ++j) {
                unsigned int ub = __builtin_bit_cast(unsigned int, f[j]);
                unsigned int hb = ub & 0xffff0000u;
                float r = f[j] - __builtin_bit_cast(float, hb);   // exact
                unsigned int rb = __builtin_bit_cast(unsigned int, r);
                unsigned int mb = rb & 0xffff0000u;
                float r2 = r - __builtin_bit_cast(float, mb);     // exact
                unsigned int lb = __builtin_bit_cast(unsigned int, r2);
                fh.u[j] = (unsigned short)(hb >> 16);
                fm.u[j] = (unsigned short)(mb >> 16);
                fl.u[j] = (unsigned short)(lb >> 16);
            }
            Ah[mt] = fh.v; Am[mt] = fm.v; Al[mt] = fl.v;
        }

        // 6 passes: hh + hm + mh + mm + hl + lh
#pragma unroll
        for (int mt = 0; mt < 2; ++mt)
#pragma unroll
            for (int nt = 0; nt < 2; ++nt) {
                short8 Bh = __builtin_bit_cast(short8, cb[nt][0]);
                short8 Bm = __builtin_bit_cast(short8, cb[nt][1]);
                short8 Bl = __builtin_bit_cast(short8, cb[nt][2]);
                floatx4 a = acc[mt][nt];
                a = __builtin_amdgcn_mfma_f32_16x16x32_bf16(Ah[mt], Bh, a, 0, 0, 0);
                a = __builtin_amdgcn_mfma_f32_16x16x32_bf16(Ah[mt], Bm, a, 0, 0, 0);
                a = __builtin_amdgcn_mfma_f32_16x16x32_bf16(Am[mt], Bh, a, 0, 0, 0);
                a = __builtin_amdgcn_mfma_f32_16x16x32_bf16(Am[mt], Bm, a, 0, 0, 0);
                a = __builtin_amdgcn_mfma_f32_16x16x32_bf16(Ah[mt], Bl, a, 0, 0, 0);
                a = __builtin_amdgcn_mfma_f32_16x16x32_bf16(Al[mt], Bh, a, 0, 0, 0);
                acc[mt][nt] = a;
            }
        __builtin_amdgcn_sched_barrier(0);   // pin: compute before stage-write

        // write window c+2 into slot (c+2)%3 (reg -> LDS); the implicit
        // vmcnt wait on n0/n1 lands after a full phase of compute
        if (c + 2 < 8) {
            float* nb = As + ws2 * 8192;
            *(float4*)(nb + wofs0) = n0;
            *(float4*)(nb + wofs1) = n1;
        }
        __syncthreads();   // publish slot ws2; order phase-c reads before reuse
        rs  = (rs  == 2) ? 0 : rs  + 1;
        ws2 = (ws2 == 2) ? 0 : ws2 + 1;
    }

    // after the final in-loop barrier all As reads are done -> overlay lg
    // partial logits -> lg. D layout: n(expert) = lane&15, m(token) = q*4+reg
#pragma unroll
    for (int mt = 0; mt < 2; ++mt)
#pragma unroll
        for (int nt = 0; nt < 2; ++nt)
#pragma unroll
            for (int r = 0; r < 4; ++r)
                lg[kq * 2048 + (mt * 16 + q * 4 + r) * 64 + nh * 32 + nt * 16 + cl]
                    = acc[mt][nt][r];
    __syncthreads();

    // ---- epilogue (verified rounds 0-8): lane = expert, 2 tokens/wave ----
    float usage_acc = 0.f;
#pragma unroll 1
    for (int j = 0; j < 2; ++j) {
        const int tl = wv * 2 + j;
        const int t  = t0 + tl;
        float l = (((lg[0 * 2048 + tl * 64 + lane] + lg[1 * 2048 + tl * 64 + lane]) +
                    (lg[2 * 2048 + tl * 64 + lane] + lg[3 * 2048 + tl * 64 + lane])) +
                   ((lg[4 * 2048 + tl * 64 + lane] + lg[5 * 2048 + tl * 64 + lane]) +
                    (lg[6 * 2048 + tl * 64 + lane] + lg[7 * 2048 + tl * 64 + lane])));

        float v1 = l; int i1 = lane;
#pragma unroll
        for (int off = 32; off >= 1; off >>= 1) {
            float ov = __shfl_xor(v1, off, 64);
            int   oi = __shfl_xor(i1, off, 64);
            if (ov > v1 || (ov == v1 && oi < i1)) { v1 = ov; i1 = oi; }
        }
        float lm = (lane == i1) ? -INFINITY : l;
        float v2 = lm; int i2 = lane;
#pragma unroll
        for (int off = 32; off >= 1; off >>= 1) {
            float ov = __shfl_xor(v2, off, 64);
            int   oi = __shfl_xor(i2, off, 64);
            if (ov > v2 || (ov == v2 && oi < i2)) { v2 = ov; i2 = oi; }
        }

        float p = expf(l - v1);
        float s = p;
#pragma unroll
        for (int off = 32; off >= 1; off >>= 1) s += __shfl_xor(s, off, 64);

        float e2  = expf(v2 - v1);
        float rcp = 1.0f / (1.0f + e2);
        usage_acc += p / s;

        if (lane == 0) {
            out[(size_t)t * 2 + 0]         = (float)i1;
            out[(size_t)t * 2 + 1]         = (float)i2;
            out[32768 + (size_t)t * 2 + 0] = rcp;
            out[32768 + (size_t)t * 2 + 1] = e2 * rcp;
        }
    }

    // per-block usage partials (no atomics; deterministic)
    ured[wv][lane] = usage_acc;
    __syncthreads();
    if (wv == 0) {
        float s = (((ured[0][lane] + ured[1][lane]) + (ured[2][lane] + ured[3][lane])) +
                   ((ured[4][lane] + ured[5][lane]) + (ured[6][lane] + ured[7][lane]))) +
                  (((ured[8][lane] + ured[9][lane]) + (ured[10][lane] + ured[11][lane])) +
                   ((ured[12][lane] + ured[13][lane]) + (ured[14][lane] + ured[15][lane])));
        usage_part[(size_t)blockIdx.x * 64 + lane] = s;
    }
}

__global__ __launch_bounds__(1024)
void router_aux(const float* __restrict__ usage_part, float* __restrict__ out) {
    __shared__ float red[16][NE];
    const int tid = threadIdx.x;    // 1024
    const int e   = tid & 63;
    const int g   = tid >> 6;       // 0..15
    float s = 0.f;
#pragma unroll
    for (int i = 0; i < NBLK / 16; ++i)
        s += usage_part[(size_t)(g * (NBLK / 16) + i) * 64 + e];
    red[g][e] = s;
    __syncthreads();
    if (g == 0) {
        float tot = 0.f;
#pragma unroll
        for (int i = 0; i < 16; ++i) tot += red[i][e];
        float u = tot * (1.0f / 16384.0f) - (1.0f / 64.0f);
        float sq = u * u;
#pragma unroll
        for (int off = 32; off >= 1; off >>= 1) sq += __shfl_xor(sq, off, 64);
        if (e == 0) out[65536] = sq;
    }
}

extern "C" void kernel_launch(void* const* d_in, const int* in_sizes, int n_in,
                              void* d_out, int out_size, void* d_ws, size_t ws_size,
                              hipStream_t stream) {
    const float* x = (const float*)d_in[0];   // [4,4096,2048] fp32
    const float* W = (const float*)d_in[1];   // [64,2048] fp32
    float* out     = (float*)d_out;           // 65537 floats

    // ws layout: Wh | Wm | Wl (packed bf16 planes, 256 KB each) | usage partials
    unsigned short* ws_h = (unsigned short*)d_ws;
    unsigned short* ws_m = ws_h + NPLANE;
    unsigned short* ws_l = ws_m + NPLANE;
    float* upart         = (float*)(ws_l + NPLANE);

    wsplit_kernel<<<dim3(NPLANE / 256), dim3(256), 0, stream>>>(W, ws_h, ws_m, ws_l);
    router_main<<<dim3(NBLK), dim3(1024), 0, stream>>>(x, ws_h, ws_m, ws_l, out, upart);
    router_aux<<<dim3(1), dim3(1024), 0, stream>>>(upart, out);
}